// Round 13
// baseline (208.088 us; speedup 1.0000x reference)
//
#include <hip/hip_runtime.h>
#include <hip/hip_bf16.h>

// SimCLR NT-Xent loss. B=4096, D=256, N=2B=8192 rows.
// loss = (1/N) sum_i [ log(denom_i) - log(pos_i) ]
//   denom_i = sum_{j!=i} exp(2*sim_ij),  pos_i = cos(z_i, z_{i+-B}) (fp32 path)
//
// R13 = R12 schedule (2080 triangular 128x128 fp8 scaled-MFMA blocks,
// verified absmax 0.0) with:
//  (a) A-fragments loaded once per tile straight global->VGPR (no sA, no
//      A ds_reads, no A staging drain). LDS = 2x16 KB B double-buffer.
//  (b) loss reduction fused into the LAST denom block via completion
//      counter (R5's abort is now attributed to a 64 KB LDS-cap overflow,
//      not the tail: sA+sB+sLast = 65556 B > 65536. Here LDS = 32 KB.)
// 2 dispatches total (was 3).

#define NROWS 8192
#define BHALF 4096
#define DDIM  256
#define NTILE 2080

typedef __attribute__((ext_vector_type(4))) int   i32x4;
typedef __attribute__((ext_vector_type(8))) int   i32x8;
typedef __attribute__((ext_vector_type(4))) float f32x4;

#define SCALE1 0x7F7F7F7F               // e8m0 biased-127 = 2^0 in every byte
#define TWO_LOG2E 2.8853900817779268f   // 2/ln(2): exp(2x) = exp2(x*TWO_LOG2E)

__device__ __forceinline__ void load_lds16(const unsigned char* g, unsigned char* l) {
    __builtin_amdgcn_global_load_lds(
        (const __attribute__((address_space(1))) void*)g,
        (__attribute__((address_space(3))) void*)l, 16, 0, 0);
}

// Kernel 1: norms + fp8-normalized matrix + positive-pair log partials +
// denom zero-init + counter zero-init.
__global__ __launch_bounds__(256) void prep_kernel(const float* __restrict__ z1,
                                                   const float* __restrict__ z2,
                                                   unsigned char* __restrict__ zn8,
                                                   float* __restrict__ posPart,
                                                   float* __restrict__ denom,
                                                   unsigned int* __restrict__ counter) {
    __shared__ float sp[4];
    int wave = threadIdx.x >> 6;
    int lane = threadIdx.x & 63;
    int i    = blockIdx.x * 4 + wave;
    float4 a = reinterpret_cast<const float4*>(z1 + (size_t)i * DDIM)[lane];
    float4 b = reinterpret_cast<const float4*>(z2 + (size_t)i * DDIM)[lane];
    float ss1 = a.x * a.x + a.y * a.y + a.z * a.z + a.w * a.w;
    float ss2 = b.x * b.x + b.y * b.y + b.z * b.z + b.w * b.w;
    float dd  = a.x * b.x + a.y * b.y + a.z * b.z + a.w * b.w;
    #pragma unroll
    for (int off = 32; off; off >>= 1) {
        ss1 += __shfl_xor(ss1, off);
        ss2 += __shfl_xor(ss2, off);
        dd  += __shfl_xor(dd, off);
    }
    float n1 = fmaxf(sqrtf(ss1), 1e-8f);
    float n2 = fmaxf(sqrtf(ss2), 1e-8f);
    float i1 = 1.0f / n1, i2 = 1.0f / n2;
    int pa = __builtin_amdgcn_cvt_pk_fp8_f32(a.x * i1, a.y * i1, 0, 0);
    pa     = __builtin_amdgcn_cvt_pk_fp8_f32(a.z * i1, a.w * i1, pa, 1);
    int pb = __builtin_amdgcn_cvt_pk_fp8_f32(b.x * i2, b.y * i2, 0, 0);
    pb     = __builtin_amdgcn_cvt_pk_fp8_f32(b.z * i2, b.w * i2, pb, 1);
    reinterpret_cast<int*>(zn8 + (size_t)i * DDIM)[lane] = pa;
    reinterpret_cast<int*>(zn8 + (size_t)(i + BHALF) * DDIM)[lane] = pb;
    if (lane == 0) sp[wave] = __logf(dd * i1 * i2);
    if (threadIdx.x < 8) denom[blockIdx.x * 8 + threadIdx.x] = 0.0f;
    if (blockIdx.x == 0 && threadIdx.x == 64) *counter = 0u;
    __syncthreads();
    if (threadIdx.x == 0)
        posPart[blockIdx.x] = sp[0] + sp[1] + sp[2] + sp[3];
}

// Kernel 2: fp8 MFMA sim-GEMM + exp row/col-sums, upper-triangular 128x128
// tiles; A direct global->VGPR; B double-buffered (2x16 KB, prefetched);
// fused final loss reduction in the last-arriving block.
__global__ __launch_bounds__(256, 3) void denom_kernel(const unsigned char* __restrict__ zn8,
                                                       float* __restrict__ denom,
                                                       const float* __restrict__ posPart,
                                                       unsigned int* __restrict__ counter,
                                                       float* __restrict__ out) {
    __shared__ __align__(16) unsigned char sB[2][64 * DDIM];   // 2 x 16 KB
    __shared__ unsigned int sLast;

    // triangular decode: 65x32 grid -> {(bi,bj) : 0 <= bi <= bj < 64}
    int x = blockIdx.x, y = blockIdx.y;
    int bi, bj;
    if (x > y) { bi = y;      bj = x - 1;  }
    else       { bi = 63 - y; bj = 63 - x; }
    int iBase = bi * 128;
    int jBase = bj * 128;
    bool isDiag = (bi == bj);

    int t    = threadIdx.x;
    int lane = t & 63;
    int wave = t >> 6;
    int col  = lane & 15;
    int quad = lane >> 4;
    int wm = wave >> 1, wn = wave & 1;

    // staging addresses (granule id = q*256 + t; row = q*16 + rowL;
    // slot pos (t&15) holds k-chunk (t&15)^rowL — verified XOR swizzle)
    int rowL  = t >> 4;
    int chunk = (t & 15) ^ rowL;

    // ---- stage B half 0; load A-fragments straight global->VGPR ----
    {
        const unsigned char* gB = zn8 + (size_t)(jBase + rowL) * DDIM + chunk * 16;
        #pragma unroll
        for (int q = 0; q < 4; q++)
            load_lds16(gB + q * 4096, sB[0] + t * 16 + q * 4096);
    }
    i32x8 af[4][2];
    {
        // A[m = wm*64 + mt*16 + col][k bytes ks*128 + quad*32 .. +32)
        const unsigned char* aBase =
            zn8 + (size_t)(iBase + wm * 64 + col) * DDIM + quad * 32;
        #pragma unroll
        for (int mt = 0; mt < 4; mt++)
            #pragma unroll
            for (int ks = 0; ks < 2; ks++) {
                const i32x4* p = (const i32x4*)(aBase + mt * 16 * DDIM + ks * 128);
                af[mt][ks] = __builtin_shufflevector(p[0], p[1], 0, 1, 2, 3, 4, 5, 6, 7);
            }
    }
    __syncthreads();   // drains B0 (and the A loads, which are needed now anyway)

    // ---- prefetch B half 1 (flies during half-0 compute) ----
    {
        const unsigned char* gB = zn8 + (size_t)(jBase + 64 + rowL) * DDIM + chunk * 16;
        #pragma unroll
        for (int q = 0; q < 4; q++)
            load_lds16(gB + q * 4096, sB[1] + t * 16 + q * 4096);
    }

    float rs[4][4];
    #pragma unroll
    for (int mt = 0; mt < 4; mt++)
        #pragma unroll
        for (int r = 0; r < 4; r++) rs[mt][r] = 0.f;

    #pragma unroll
    for (int h = 0; h < 2; h++) {
        if (h) __syncthreads();          // drains B1 (issued one compute phase ago)
        const unsigned char* bRow = sB[h] + (size_t)(wn * 32 + col) * DDIM;

        i32x8 bfr[2][2];
        #pragma unroll
        for (int nt = 0; nt < 2; nt++)
            #pragma unroll
            for (int ks = 0; ks < 2; ks++) {
                int g0 = ks * 8 + quad * 2;
                i32x4 lo = *(const i32x4*)(bRow + nt * 16 * DDIM + ((g0    ) ^ col) * 16);
                i32x4 hi = *(const i32x4*)(bRow + nt * 16 * DDIM + ((g0 + 1) ^ col) * 16);
                bfr[nt][ks] = __builtin_shufflevector(lo, hi, 0, 1, 2, 3, 4, 5, 6, 7);
            }

        float cs[2] = {0.f, 0.f};
        #pragma unroll
        for (int mt = 0; mt < 4; mt++) {
            int gi = iBase + wm * 64 + mt * 16;
            #pragma unroll
            for (int nt = 0; nt < 2; nt++) {
                f32x4 acc = {0.f, 0.f, 0.f, 0.f};
                acc = __builtin_amdgcn_mfma_scale_f32_16x16x128_f8f6f4(
                          af[mt][0], bfr[nt][0], acc, 0, 0, 0, SCALE1, 0, SCALE1);
                acc = __builtin_amdgcn_mfma_scale_f32_16x16x128_f8f6f4(
                          af[mt][1], bfr[nt][1], acc, 0, 0, 0, SCALE1, 0, SCALE1);
                bool dtile = (gi == jBase + h * 64 + wn * 32 + nt * 16);
                float csl = 0.f;
                #pragma unroll
                for (int r = 0; r < 4; r++) {
                    float e = exp2f(acc[r] * TWO_LOG2E);
                    if (dtile && (quad * 4 + r) == col) e = 0.f;
                    rs[mt][r] += e;
                    csl += e;
                }
                cs[nt] += csl;
            }
        }

        if (!isDiag) {
            #pragma unroll
            for (int nt = 0; nt < 2; nt++) {
                float v = cs[nt];
                v += __shfl_xor(v, 16);
                v += __shfl_xor(v, 32);
                if (quad == 0)
                    atomicAdd(&denom[jBase + h * 64 + wn * 32 + nt * 16 + col], v);
            }
        }
    }

    // ---- row-sums: reduce 16 col-lanes, combine wn pair via LDS, 128 atomics ----
    #pragma unroll
    for (int mt = 0; mt < 4; mt++)
        #pragma unroll
        for (int r = 0; r < 4; r++) {
            float v = rs[mt][r];
            v += __shfl_xor(v, 1);
            v += __shfl_xor(v, 2);
            v += __shfl_xor(v, 4);
            v += __shfl_xor(v, 8);
            rs[mt][r] = v;
        }
    __syncthreads();                     // all tile reads done; sB reusable
    float* red = (float*)sB[0];
    if (col == 0) {
        #pragma unroll
        for (int mt = 0; mt < 4; mt++)
            #pragma unroll
            for (int r = 0; r < 4; r++)
                red[wn * 128 + wm * 64 + mt * 16 + quad * 4 + r] = rs[mt][r];
    }
    __syncthreads();
    if (t < 128)
        atomicAdd(&denom[iBase + t], red[t] + red[128 + t]);

    // ---- fused final reduction: last-arriving block computes the loss ----
    __threadfence();
    if (t == 0) {
        unsigned int old = atomicAdd(counter, 1u);
        sLast = (old == NTILE - 1u) ? 1u : 0u;
    }
    __syncthreads();
    if (sLast) {
        float s = 0.f;
        for (int i = t; i < NROWS; i += 256)
            s += __logf(atomicAdd(&denom[i], 0.0f));   // coherent device-scope read
        for (int i = t; i < BHALF / 4; i += 256)
            s -= 2.0f * posPart[i];
        #pragma unroll
        for (int off = 32; off; off >>= 1) s += __shfl_xor(s, off);
        float* sRed = red;               // reuse LDS scratch
        if ((t & 63) == 0) sRed[t >> 6] = s;
        __syncthreads();
        if (t == 0)
            out[0] = (sRed[0] + sRed[1] + sRed[2] + sRed[3]) * (1.0f / NROWS);
    }
}

extern "C" void kernel_launch(void* const* d_in, const int* in_sizes, int n_in,
                              void* d_out, int out_size, void* d_ws, size_t ws_size,
                              hipStream_t stream) {
    const float* z1 = (const float*)d_in[0];
    const float* z2 = (const float*)d_in[1];

    // ws: zn8 fp8 [8192*256] (2 MB) | denom f32[8192] | posPart f32[1024] | counter
    unsigned char* zn8 = (unsigned char*)d_ws;
    float* denom   = (float*)((char*)d_ws + (size_t)NROWS * DDIM);
    float* posPart = denom + NROWS;
    unsigned int* counter = (unsigned int*)(posPart + BHALF / 4);

    prep_kernel<<<BHALF / 4, 256, 0, stream>>>(z1, z2, zn8, posPart, denom, counter);
    denom_kernel<<<dim3(65, 32), 256, 0, stream>>>(zn8, denom, posPart, counter,
                                                   (float*)d_out);
}

// Round 14
// 204.020 us; speedup vs baseline: 1.0199x; 1.0199x over previous
//
#include <hip/hip_runtime.h>
#include <hip/hip_bf16.h>

// SimCLR NT-Xent loss. B=4096, D=256, N=2B=8192 rows.
// loss = (1/N) sum_i [ log(denom_i) - log(pos_i) ]
//   denom_i = sum_{j!=i} exp(2*sim_ij),  pos_i = cos(z_i, z_{i+-B}) (fp32 path)
//
// R14 = R12 denom core VERBATIM (best: 86.3 us; triangular 128x128 fp8
// scaled-MFMA, LDS-sourced A-frags, aliased B1 prefetch, 48 KB, 3 blocks/CU)
// + R13's VERIFIED fused last-block loss tail (counter + threadfence +
// coherent atomic read-back; LDS 48 KB + 4 B, safely under the 64 KB cap
// that killed R5). Deletes the loss_kernel dispatch + gap.
// THREE-STRIKE LAW (R1, R3/R4, R13): A-fragments direct global->VGPR always
// loses (compiler rematerializes into serial load->MFMA chains); A must go
// via global_load_lds -> ds_read. Do not try again.

#define NROWS 8192
#define BHALF 4096
#define DDIM  256
#define NTILE 2080

typedef __attribute__((ext_vector_type(4))) int   i32x4;
typedef __attribute__((ext_vector_type(8))) int   i32x8;
typedef __attribute__((ext_vector_type(4))) float f32x4;

#define SCALE1 0x7F7F7F7F               // e8m0 biased-127 = 2^0 in every byte
#define TWO_LOG2E 2.8853900817779268f   // 2/ln(2): exp(2x) = exp2(x*TWO_LOG2E)

__device__ __forceinline__ void load_lds16(const unsigned char* g, unsigned char* l) {
    __builtin_amdgcn_global_load_lds(
        (const __attribute__((address_space(1))) void*)g,
        (__attribute__((address_space(3))) void*)l, 16, 0, 0);
}

// Kernel 1: norms + fp8-normalized matrix + positive-pair log partials +
// denom zero-init + counter zero-init.
__global__ __launch_bounds__(256) void prep_kernel(const float* __restrict__ z1,
                                                   const float* __restrict__ z2,
                                                   unsigned char* __restrict__ zn8,
                                                   float* __restrict__ posPart,
                                                   float* __restrict__ denom,
                                                   unsigned int* __restrict__ counter) {
    __shared__ float sp[4];
    int wave = threadIdx.x >> 6;
    int lane = threadIdx.x & 63;
    int i    = blockIdx.x * 4 + wave;
    float4 a = reinterpret_cast<const float4*>(z1 + (size_t)i * DDIM)[lane];
    float4 b = reinterpret_cast<const float4*>(z2 + (size_t)i * DDIM)[lane];
    float ss1 = a.x * a.x + a.y * a.y + a.z * a.z + a.w * a.w;
    float ss2 = b.x * b.x + b.y * b.y + b.z * b.z + b.w * b.w;
    float dd  = a.x * b.x + a.y * b.y + a.z * b.z + a.w * b.w;
    #pragma unroll
    for (int off = 32; off; off >>= 1) {
        ss1 += __shfl_xor(ss1, off);
        ss2 += __shfl_xor(ss2, off);
        dd  += __shfl_xor(dd, off);
    }
    float n1 = fmaxf(sqrtf(ss1), 1e-8f);
    float n2 = fmaxf(sqrtf(ss2), 1e-8f);
    float i1 = 1.0f / n1, i2 = 1.0f / n2;
    int pa = __builtin_amdgcn_cvt_pk_fp8_f32(a.x * i1, a.y * i1, 0, 0);
    pa     = __builtin_amdgcn_cvt_pk_fp8_f32(a.z * i1, a.w * i1, pa, 1);
    int pb = __builtin_amdgcn_cvt_pk_fp8_f32(b.x * i2, b.y * i2, 0, 0);
    pb     = __builtin_amdgcn_cvt_pk_fp8_f32(b.z * i2, b.w * i2, pb, 1);
    reinterpret_cast<int*>(zn8 + (size_t)i * DDIM)[lane] = pa;
    reinterpret_cast<int*>(zn8 + (size_t)(i + BHALF) * DDIM)[lane] = pb;
    if (lane == 0) sp[wave] = __logf(dd * i1 * i2);
    if (threadIdx.x < 8) denom[blockIdx.x * 8 + threadIdx.x] = 0.0f;
    if (blockIdx.x == 0 && threadIdx.x == 64) *counter = 0u;
    __syncthreads();
    if (threadIdx.x == 0)
        posPart[blockIdx.x] = sp[0] + sp[1] + sp[2] + sp[3];
}

// Kernel 2: fp8 MFMA sim-GEMM + exp row/col-sums, upper-triangular 128x128
// tiles. LDS 48 KB: A(32 KB, consumed to regs via ds_read) aliased by
// B1(16 KB) + B0(16 KB). Fused last-block loss reduction.
__global__ __launch_bounds__(256, 3) void denom_kernel(const unsigned char* __restrict__ zn8,
                                                       float* __restrict__ denom,
                                                       const float* __restrict__ posPart,
                                                       unsigned int* __restrict__ counter,
                                                       float* __restrict__ out) {
    __shared__ __align__(16) unsigned char sMem[48 * 1024];
    __shared__ unsigned int sLast;
    unsigned char* sA  = sMem;            // 32 KB, read into regs then dead
    unsigned char* sB0 = sMem + 32768;    // 16 KB
    unsigned char* sB1 = sMem;            // aliases A's first 16 KB

    // triangular decode: 65x32 grid -> {(bi,bj) : 0 <= bi <= bj < 64}
    int x = blockIdx.x, y = blockIdx.y;
    int bi, bj;
    if (x > y) { bi = y;      bj = x - 1;  }
    else       { bi = 63 - y; bj = 63 - x; }
    int iBase = bi * 128;
    int jBase = bj * 128;
    bool isDiag = (bi == bj);

    int t    = threadIdx.x;
    int lane = t & 63;
    int wave = t >> 6;
    int col  = lane & 15;
    int quad = lane >> 4;
    int wm = wave >> 1, wn = wave & 1;

    // staging addresses (granule id = q*256 + t; row = q*16 + rowL;
    // slot pos (t&15) holds k-chunk (t&15)^rowL — verified XOR swizzle)
    int rowL  = t >> 4;
    int chunk = (t & 15) ^ rowL;

    // ---- stage A (128 rows) + B half 0 (64 rows) ----
    {
        const unsigned char* gA = zn8 + (size_t)(iBase + rowL) * DDIM + chunk * 16;
        #pragma unroll
        for (int q = 0; q < 8; q++)
            load_lds16(gA + q * 4096, sA + t * 16 + q * 4096);
        const unsigned char* gB = zn8 + (size_t)(jBase + rowL) * DDIM + chunk * 16;
        #pragma unroll
        for (int q = 0; q < 4; q++)
            load_lds16(gB + q * 4096, sB0 + t * 16 + q * 4096);
    }
    __syncthreads();

    // ---- A-fragments -> registers (once per tile, via ds_read) ----
    i32x8 af[4][2];
    {
        const unsigned char* aRow = sA + (size_t)(wm * 64 + col) * DDIM;
        #pragma unroll
        for (int mt = 0; mt < 4; mt++)
            #pragma unroll
            for (int ks = 0; ks < 2; ks++) {
                int g0 = ks * 8 + quad * 2;
                i32x4 lo = *(const i32x4*)(aRow + mt * 16 * DDIM + ((g0    ) ^ col) * 16);
                i32x4 hi = *(const i32x4*)(aRow + mt * 16 * DDIM + ((g0 + 1) ^ col) * 16);
                af[mt][ks] = __builtin_shufflevector(lo, hi, 0, 1, 2, 3, 4, 5, 6, 7);
            }
    }
    __syncthreads();   // all waves done with sA (lgkm-only drain: cheap)

    // ---- prefetch B half 1 into sB1 (flies during half-0 compute) ----
    {
        const unsigned char* gB = zn8 + (size_t)(jBase + 64 + rowL) * DDIM + chunk * 16;
        #pragma unroll
        for (int q = 0; q < 4; q++)
            load_lds16(gB + q * 4096, sB1 + t * 16 + q * 4096);
    }

    float rs[4][4];                     // row-sums, accumulated over both halves
    #pragma unroll
    for (int mt = 0; mt < 4; mt++)
        #pragma unroll
        for (int r = 0; r < 4; r++) rs[mt][r] = 0.f;

    #pragma unroll
    for (int h = 0; h < 2; h++) {
        if (h) __syncthreads();          // drains B1 (issued one compute phase ago)
        const unsigned char* bRow =
            (h ? sB1 : sB0) + (size_t)(wn * 32 + col) * DDIM;

        // B fragments: row' = wn*32 + nt*16 + col (row'&15 == col)
        i32x8 bfr[2][2];
        #pragma unroll
        for (int nt = 0; nt < 2; nt++)
            #pragma unroll
            for (int ks = 0; ks < 2; ks++) {
                int g0 = ks * 8 + quad * 2;
                i32x4 lo = *(const i32x4*)(bRow + nt * 16 * DDIM + ((g0    ) ^ col) * 16);
                i32x4 hi = *(const i32x4*)(bRow + nt * 16 * DDIM + ((g0 + 1) ^ col) * 16);
                bfr[nt][ks] = __builtin_shufflevector(lo, hi, 0, 1, 2, 3, 4, 5, 6, 7);
            }

        float cs[2] = {0.f, 0.f};
        #pragma unroll
        for (int mt = 0; mt < 4; mt++) {
            int gi = iBase + wm * 64 + mt * 16;
            #pragma unroll
            for (int nt = 0; nt < 2; nt++) {
                f32x4 acc = {0.f, 0.f, 0.f, 0.f};
                acc = __builtin_amdgcn_mfma_scale_f32_16x16x128_f8f6f4(
                          af[mt][0], bfr[nt][0], acc, 0, 0, 0, SCALE1, 0, SCALE1);
                acc = __builtin_amdgcn_mfma_scale_f32_16x16x128_f8f6f4(
                          af[mt][1], bfr[nt][1], acc, 0, 0, 0, SCALE1, 0, SCALE1);
                bool dtile = (gi == jBase + h * 64 + wn * 32 + nt * 16);
                float csl = 0.f;
                #pragma unroll
                for (int r = 0; r < 4; r++) {
                    float e = exp2f(acc[r] * TWO_LOG2E);
                    if (dtile && (quad * 4 + r) == col) e = 0.f;
                    rs[mt][r] += e;
                    csl += e;
                }
                cs[nt] += csl;
            }
        }

        // col-sums for this half (off-diag tiles only)
        if (!isDiag) {
            #pragma unroll
            for (int nt = 0; nt < 2; nt++) {
                float v = cs[nt];
                v += __shfl_xor(v, 16);
                v += __shfl_xor(v, 32);
                if (quad == 0)
                    atomicAdd(&denom[jBase + h * 64 + wn * 32 + nt * 16 + col], v);
            }
        }
    }

    // ---- row-sums: reduce 16 col-lanes, combine wn pair via LDS, 128 atomics ----
    #pragma unroll
    for (int mt = 0; mt < 4; mt++)
        #pragma unroll
        for (int r = 0; r < 4; r++) {
            float v = rs[mt][r];
            v += __shfl_xor(v, 1);
            v += __shfl_xor(v, 2);
            v += __shfl_xor(v, 4);
            v += __shfl_xor(v, 8);
            rs[mt][r] = v;
        }
    __syncthreads();                     // all compute reads done
    float* red = (float*)(sMem + 16384); // scratch region, no live aliasing
    if (col == 0) {
        #pragma unroll
        for (int mt = 0; mt < 4; mt++)
            #pragma unroll
            for (int r = 0; r < 4; r++)
                red[wn * 128 + wm * 64 + mt * 16 + quad * 4 + r] = rs[mt][r];
    }
    __syncthreads();
    if (t < 128)
        atomicAdd(&denom[iBase + t], red[t] + red[128 + t]);

    // ---- fused final reduction: last-arriving block computes the loss ----
    __threadfence();
    if (t == 0) {
        unsigned int old = atomicAdd(counter, 1u);
        sLast = (old == NTILE - 1u) ? 1u : 0u;
    }
    __syncthreads();
    if (sLast) {
        float s = 0.f;
        for (int i = t; i < NROWS; i += 256)
            s += __logf(atomicAdd(&denom[i], 0.0f));   // coherent device-scope read
        for (int i = t; i < BHALF / 4; i += 256)
            s -= 2.0f * posPart[i];
        #pragma unroll
        for (int off = 32; off; off >>= 1) s += __shfl_xor(s, off);
        if ((t & 63) == 0) red[t >> 6] = s;
        __syncthreads();
        if (t == 0)
            out[0] = (red[0] + red[1] + red[2] + red[3]) * (1.0f / NROWS);
    }
}

extern "C" void kernel_launch(void* const* d_in, const int* in_sizes, int n_in,
                              void* d_out, int out_size, void* d_ws, size_t ws_size,
                              hipStream_t stream) {
    const float* z1 = (const float*)d_in[0];
    const float* z2 = (const float*)d_in[1];

    // ws: zn8 fp8 [8192*256] (2 MB) | denom f32[8192] | posPart f32[1024] | counter
    unsigned char* zn8 = (unsigned char*)d_ws;
    float* denom   = (float*)((char*)d_ws + (size_t)NROWS * DDIM);
    float* posPart = denom + NROWS;
    unsigned int* counter = (unsigned int*)(posPart + BHALF / 4);

    prep_kernel<<<BHALF / 4, 256, 0, stream>>>(z1, z2, zn8, posPart, denom, counter);
    denom_kernel<<<dim3(65, 32), 256, 0, stream>>>(zn8, denom, posPart, counter,
                                                   (float*)d_out);
}

// Round 15
// 89.946 us; speedup vs baseline: 2.3135x; 2.2682x over previous
//
#include <hip/hip_runtime.h>
#include <hip/hip_bf16.h>

// SimCLR NT-Xent loss. B=4096, D=256, N=2B=8192 rows.
// loss = (1/N) sum_i [ log(denom_i) - log(pos_i) ]
//   denom_i = sum_{j!=i} exp(2*sim_ij),  pos_i = cos(z_i, z_{i+-B}) (fp32 path)
//
// R15 = R12 3-dispatch structure (FUSED TAIL IS BANNED: R13+R14 both showed
// the identical VGPR=76/MfmaUtil=2% collapse with it; R12 without it = 86.3us)
// + denom at 40 KB LDS -> 4 blocks/CU: B staged in EIGHT 16-row (4 KB)
// double-buffered prefetched stages. Tile/tile-work invariants vs R12: same
// 128x128 tile, same staging instr count, same ds_read count, same exp count,
// same 256 atomics/tile (col partials via per-wave LDS slots in dead sA).
// Rounds: 2080/1024 = 2.03 (was 2.71).
// THREE-STRIKE LAW: A-frags direct global->VGPR always loses; A goes
// global_load_lds -> ds_read only.

#define NROWS 8192
#define BHALF 4096
#define DDIM  256

typedef __attribute__((ext_vector_type(4))) int   i32x4;
typedef __attribute__((ext_vector_type(8))) int   i32x8;
typedef __attribute__((ext_vector_type(4))) float f32x4;

#define SCALE1 0x7F7F7F7F               // e8m0 biased-127 = 2^0 in every byte
#define TWO_LOG2E 2.8853900817779268f   // 2/ln(2): exp(2x) = exp2(x*TWO_LOG2E)

__device__ __forceinline__ void load_lds16(const unsigned char* g, unsigned char* l) {
    __builtin_amdgcn_global_load_lds(
        (const __attribute__((address_space(1))) void*)g,
        (__attribute__((address_space(3))) void*)l, 16, 0, 0);
}

// Kernel 1: norms + fp8-normalized matrix + positive-pair log partials +
// denom zero-init + out zero-init. (R12 verbatim, verified)
__global__ __launch_bounds__(256) void prep_kernel(const float* __restrict__ z1,
                                                   const float* __restrict__ z2,
                                                   unsigned char* __restrict__ zn8,
                                                   float* __restrict__ posPart,
                                                   float* __restrict__ denom,
                                                   float* __restrict__ out) {
    __shared__ float sp[4];
    int wave = threadIdx.x >> 6;
    int lane = threadIdx.x & 63;
    int i    = blockIdx.x * 4 + wave;
    float4 a = reinterpret_cast<const float4*>(z1 + (size_t)i * DDIM)[lane];
    float4 b = reinterpret_cast<const float4*>(z2 + (size_t)i * DDIM)[lane];
    float ss1 = a.x * a.x + a.y * a.y + a.z * a.z + a.w * a.w;
    float ss2 = b.x * b.x + b.y * b.y + b.z * b.z + b.w * b.w;
    float dd  = a.x * b.x + a.y * b.y + a.z * b.z + a.w * b.w;
    #pragma unroll
    for (int off = 32; off; off >>= 1) {
        ss1 += __shfl_xor(ss1, off);
        ss2 += __shfl_xor(ss2, off);
        dd  += __shfl_xor(dd, off);
    }
    float n1 = fmaxf(sqrtf(ss1), 1e-8f);
    float n2 = fmaxf(sqrtf(ss2), 1e-8f);
    float i1 = 1.0f / n1, i2 = 1.0f / n2;
    int pa = __builtin_amdgcn_cvt_pk_fp8_f32(a.x * i1, a.y * i1, 0, 0);
    pa     = __builtin_amdgcn_cvt_pk_fp8_f32(a.z * i1, a.w * i1, pa, 1);
    int pb = __builtin_amdgcn_cvt_pk_fp8_f32(b.x * i2, b.y * i2, 0, 0);
    pb     = __builtin_amdgcn_cvt_pk_fp8_f32(b.z * i2, b.w * i2, pb, 1);
    reinterpret_cast<int*>(zn8 + (size_t)i * DDIM)[lane] = pa;
    reinterpret_cast<int*>(zn8 + (size_t)(i + BHALF) * DDIM)[lane] = pb;
    if (lane == 0) sp[wave] = __logf(dd * i1 * i2);
    if (threadIdx.x < 8) denom[blockIdx.x * 8 + threadIdx.x] = 0.0f;
    if (blockIdx.x == 0 && threadIdx.x == 64) out[0] = 0.0f;
    __syncthreads();
    if (threadIdx.x == 0)
        posPart[blockIdx.x] = sp[0] + sp[1] + sp[2] + sp[3];
}

// Kernel 2: fp8 MFMA sim-GEMM + exp row/col-sums, upper-triangular 128x128
// tiles. LDS 40 KB (4 blocks/CU): sA 32K (consumed to regs, then reused as
// col-partial scratch) + 2 x 4K B stage buffers (8 stages of 16 j-rows,
// prefetch double-buffered). Wave w owns A-rows w*32..w*32+31.
__global__ __launch_bounds__(256, 4) void denom_kernel(const unsigned char* __restrict__ zn8,
                                                       float* __restrict__ denom) {
    __shared__ __align__(16) unsigned char sMem[40960];
    unsigned char* sA  = sMem;             // 32 KB, dead after A-frag reads
    unsigned char* sB0 = sMem + 32768;     // 4 KB
    unsigned char* sB1 = sMem + 36864;     // 4 KB
    float* colPart = (float*)sMem;         // [4][128] in dead sA (2 KB)

    // triangular decode: 65x32 grid -> {(bi,bj) : 0 <= bi <= bj < 64}
    int x = blockIdx.x, y = blockIdx.y;
    int bi, bj;
    if (x > y) { bi = y;      bj = x - 1;  }
    else       { bi = 63 - y; bj = 63 - x; }
    int iBase = bi * 128;
    int jBase = bj * 128;
    bool isDiag = (bi == bj);

    int t    = threadIdx.x;
    int lane = t & 63;
    int wave = t >> 6;
    int col  = lane & 15;
    int quad = lane >> 4;

    // A staging (R12-verbatim): granule id = q*256 + t; row = q*16 + rowL;
    // slot pos (t&15) holds k-chunk (t&15)^rowL.
    int rowL  = t >> 4;
    int chunkA = (t & 15) ^ rowL;
    // B stage staging: 16 rows x 256 B = 256 granules, 1/thread:
    // row = t>>4 (0..15), pos = t&15, chunk = pos^row (same invariant).
    int chunkB = (t & 15) ^ (t >> 4);
    const unsigned char* gBbase = zn8 + (size_t)(jBase + (t >> 4)) * DDIM + chunkB * 16;

    // ---- stage A (128 rows) + B stage 0 (16 rows) ----
    {
        const unsigned char* gA = zn8 + (size_t)(iBase + rowL) * DDIM + chunkA * 16;
        #pragma unroll
        for (int q = 0; q < 8; q++)
            load_lds16(gA + q * 4096, sA + t * 16 + q * 4096);
        load_lds16(gBbase, sB0 + t * 16);
    }
    __syncthreads();

    // ---- A-fragments -> registers (via ds_read; wave owns rows wave*32..+31) ----
    i32x8 af[2][2];
    {
        const unsigned char* aRow = sA + (size_t)(wave * 32 + col) * DDIM;
        #pragma unroll
        for (int mt = 0; mt < 2; mt++)
            #pragma unroll
            for (int ks = 0; ks < 2; ks++) {
                int g0 = ks * 8 + quad * 2;
                i32x4 lo = *(const i32x4*)(aRow + mt * 16 * DDIM + ((g0    ) ^ col) * 16);
                i32x4 hi = *(const i32x4*)(aRow + mt * 16 * DDIM + ((g0 + 1) ^ col) * 16);
                af[mt][ks] = __builtin_shufflevector(lo, hi, 0, 1, 2, 3, 4, 5, 6, 7);
            }
    }
    __syncthreads();   // all waves done with sA (lgkm-only drain: cheap)

    // zero this wave's col-partial slots (wave-private region, wave-ordered)
    colPart[wave * 128 + lane] = 0.0f;
    colPart[wave * 128 + 64 + lane] = 0.0f;

    // ---- prefetch B stage 1 (flies during stage-0 compute) ----
    load_lds16(gBbase + (size_t)16 * DDIM, sB1 + t * 16);

    float rs[2][4];
    #pragma unroll
    for (int mt = 0; mt < 2; mt++)
        #pragma unroll
        for (int r = 0; r < 4; r++) rs[mt][r] = 0.f;

    for (int s = 0; s < 8; s++) {
        if (s) __syncthreads();          // drains stage s (issued one phase ago)

        // prefetch stage s+1 into the other buffer
        if (s + 1 < 8)
            load_lds16(gBbase + (size_t)(s + 1) * 16 * DDIM,
                       ((s + 1) & 1 ? sB1 : sB0) + t * 16);

        // ---- compute stage s: 16 j-cols, local B-row = col ----
        const unsigned char* bRow = ((s & 1) ? sB1 : sB0) + (size_t)col * DDIM;
        i32x8 bfr[2];
        #pragma unroll
        for (int ks = 0; ks < 2; ks++) {
            int g0 = ks * 8 + quad * 2;
            i32x4 lo = *(const i32x4*)(bRow + ((g0    ) ^ col) * 16);
            i32x4 hi = *(const i32x4*)(bRow + ((g0 + 1) ^ col) * 16);
            bfr[ks] = __builtin_shufflevector(lo, hi, 0, 1, 2, 3, 4, 5, 6, 7);
        }

        float cs = 0.f;
        #pragma unroll
        for (int mt = 0; mt < 2; mt++) {
            int gi = iBase + wave * 32 + mt * 16;
            f32x4 acc = {0.f, 0.f, 0.f, 0.f};
            acc = __builtin_amdgcn_mfma_scale_f32_16x16x128_f8f6f4(
                      af[mt][0], bfr[0], acc, 0, 0, 0, SCALE1, 0, SCALE1);
            acc = __builtin_amdgcn_mfma_scale_f32_16x16x128_f8f6f4(
                      af[mt][1], bfr[1], acc, 0, 0, 0, SCALE1, 0, SCALE1);
            bool dtile = (gi == jBase + s * 16);
            #pragma unroll
            for (int r = 0; r < 4; r++) {
                float e = exp2f(acc[r] * TWO_LOG2E);
                if (dtile && (quad * 4 + r) == col) e = 0.f;
                rs[mt][r] += e;
                cs += e;
            }
        }

        // col partial for this stage (distinct 16 cols per stage -> plain store)
        if (!isDiag) {
            cs += __shfl_xor(cs, 16);
            cs += __shfl_xor(cs, 32);
            if (quad == 0)
                colPart[wave * 128 + s * 16 + col] = cs;
        }
    }

    // ---- row-sums: reduce 16 col-lanes, direct atomics (rows wave-private) ----
    #pragma unroll
    for (int mt = 0; mt < 2; mt++)
        #pragma unroll
        for (int r = 0; r < 4; r++) {
            float v = rs[mt][r];
            v += __shfl_xor(v, 1);
            v += __shfl_xor(v, 2);
            v += __shfl_xor(v, 4);
            v += __shfl_xor(v, 8);
            if (col == 0)
                atomicAdd(&denom[iBase + wave * 32 + mt * 16 + quad * 4 + r], v);
        }

    // ---- col-sums: fold 4 per-wave partials, 128 atomics ----
    __syncthreads();                     // all colPart writes visible
    if (t < 128 && !isDiag)
        atomicAdd(&denom[jBase + t],
                  colPart[t] + colPart[128 + t] + colPart[256 + t] + colPart[384 + t]);
}

// Kernel 3: final reduction, 32 blocks, atomic into prep-zeroed out[0].
__global__ __launch_bounds__(256) void loss_kernel(const float* __restrict__ posPart,
                                                   const float* __restrict__ denom,
                                                   float* __restrict__ out) {
    __shared__ float sdata[4];
    int t = threadIdx.x;
    float s = __logf(denom[blockIdx.x * 256 + t]);
    if (t < 32) s -= 2.0f * posPart[blockIdx.x * 32 + t];
    #pragma unroll
    for (int off = 32; off; off >>= 1) s += __shfl_xor(s, off);
    if ((t & 63) == 0) sdata[t >> 6] = s;
    __syncthreads();
    if (t == 0)
        atomicAdd(out, (sdata[0] + sdata[1] + sdata[2] + sdata[3]) * (1.0f / NROWS));
}

extern "C" void kernel_launch(void* const* d_in, const int* in_sizes, int n_in,
                              void* d_out, int out_size, void* d_ws, size_t ws_size,
                              hipStream_t stream) {
    const float* z1 = (const float*)d_in[0];
    const float* z2 = (const float*)d_in[1];

    // ws: zn8 fp8 [8192*256] (2 MB) | denom f32[8192] | posPart f32[1024]
    unsigned char* zn8 = (unsigned char*)d_ws;
    float* denom   = (float*)((char*)d_ws + (size_t)NROWS * DDIM);
    float* posPart = denom + NROWS;

    prep_kernel<<<BHALF / 4, 256, 0, stream>>>(z1, z2, zn8, posPart, denom, (float*)d_out);
    denom_kernel<<<dim3(65, 32), 256, 0, stream>>>(zn8, denom);
    loss_kernel<<<NROWS / 256, 256, 0, stream>>>(posPart, denom, (float*)d_out);
}

// Round 16
// 86.351 us; speedup vs baseline: 2.4098x; 1.0416x over previous
//
#include <hip/hip_runtime.h>
#include <hip/hip_bf16.h>

// SimCLR NT-Xent loss. B=4096, D=256, N=2B=8192 rows.
// loss = (1/N) sum_i [ log(denom_i) - log(pos_i) ]
//   denom_i = sum_{j!=i} exp(2*sim_ij),  pos_i = cos(z_i, z_{i+-B}) (fp32 path)
//
// R16 = R12 laws (128x128 tiles, 64-row stages, LDS-sourced frags, 48 KB /
// 3 blocks/CU, 3 dispatches, NO fused tail) + 3-tile chunks: 715 active
// blocks fit 768 residency slots in ONE round (R12: 2080 blocks = 2.71
// rounds). A staged + af read once per chunk; flat ping-pong of up to six
// 64-row B stages through 2x16 KB buffers (one in sA's dead space); one
// barrier per stage, prefetch issued post-barrier. rs accumulated across
// the chunk; epilogue once per chunk.
// Accumulated laws: fused tail BANNED (R13/R14 VGPR=76 collapse); A-frags
// direct global->VGPR BANNED (R1/R3/R13); stages thinner than 64 rows lose
// (R8/R15); schedules must keep >=3 blocks/CU (R11).

#define NROWS 8192
#define BHALF 4096
#define DDIM  256

typedef __attribute__((ext_vector_type(4))) int   i32x4;
typedef __attribute__((ext_vector_type(8))) int   i32x8;
typedef __attribute__((ext_vector_type(4))) float f32x4;

#define SCALE1 0x7F7F7F7F               // e8m0 biased-127 = 2^0 in every byte
#define TWO_LOG2E 2.8853900817779268f   // 2/ln(2): exp(2x) = exp2(x*TWO_LOG2E)

__device__ __forceinline__ void load_lds16(const unsigned char* g, unsigned char* l) {
    __builtin_amdgcn_global_load_lds(
        (const __attribute__((address_space(1))) void*)g,
        (__attribute__((address_space(3))) void*)l, 16, 0, 0);
}

// Kernel 1: norms + fp8-normalized matrix + positive-pair log partials +
// denom zero-init + out zero-init. (R12 verbatim, verified)
__global__ __launch_bounds__(256) void prep_kernel(const float* __restrict__ z1,
                                                   const float* __restrict__ z2,
                                                   unsigned char* __restrict__ zn8,
                                                   float* __restrict__ posPart,
                                                   float* __restrict__ denom,
                                                   float* __restrict__ out) {
    __shared__ float sp[4];
    int wave = threadIdx.x >> 6;
    int lane = threadIdx.x & 63;
    int i    = blockIdx.x * 4 + wave;
    float4 a = reinterpret_cast<const float4*>(z1 + (size_t)i * DDIM)[lane];
    float4 b = reinterpret_cast<const float4*>(z2 + (size_t)i * DDIM)[lane];
    float ss1 = a.x * a.x + a.y * a.y + a.z * a.z + a.w * a.w;
    float ss2 = b.x * b.x + b.y * b.y + b.z * b.z + b.w * b.w;
    float dd  = a.x * b.x + a.y * b.y + a.z * b.z + a.w * b.w;
    #pragma unroll
    for (int off = 32; off; off >>= 1) {
        ss1 += __shfl_xor(ss1, off);
        ss2 += __shfl_xor(ss2, off);
        dd  += __shfl_xor(dd, off);
    }
    float n1 = fmaxf(sqrtf(ss1), 1e-8f);
    float n2 = fmaxf(sqrtf(ss2), 1e-8f);
    float i1 = 1.0f / n1, i2 = 1.0f / n2;
    int pa = __builtin_amdgcn_cvt_pk_fp8_f32(a.x * i1, a.y * i1, 0, 0);
    pa     = __builtin_amdgcn_cvt_pk_fp8_f32(a.z * i1, a.w * i1, pa, 1);
    int pb = __builtin_amdgcn_cvt_pk_fp8_f32(b.x * i2, b.y * i2, 0, 0);
    pb     = __builtin_amdgcn_cvt_pk_fp8_f32(b.z * i2, b.w * i2, pb, 1);
    reinterpret_cast<int*>(zn8 + (size_t)i * DDIM)[lane] = pa;
    reinterpret_cast<int*>(zn8 + (size_t)(i + BHALF) * DDIM)[lane] = pb;
    if (lane == 0) sp[wave] = __logf(dd * i1 * i2);
    if (threadIdx.x < 8) denom[blockIdx.x * 8 + threadIdx.x] = 0.0f;
    if (blockIdx.x == 0 && threadIdx.x == 64) out[0] = 0.0f;
    __syncthreads();
    if (threadIdx.x == 0)
        posPart[blockIdx.x] = sp[0] + sp[1] + sp[2] + sp[3];
}

// Kernel 2: fp8 MFMA sim-GEMM + exp row/col-sums, triangular 3-tile chunks.
// LDS 48 KB: sA [0:32K) dead after af read; stage buffers buf0=[32K:48K)
// (free from start) and buf1=[16K:32K) (sA's dead space). red=[0:2K).
__global__ __launch_bounds__(256, 3) void denom_kernel(const unsigned char* __restrict__ zn8,
                                                       float* __restrict__ denom) {
    __shared__ __align__(16) unsigned char sMem[48 * 1024];
    unsigned char* sA   = sMem;
    unsigned char* buf0 = sMem + 32768;
    unsigned char* buf1 = sMem + 16384;

    int bi  = blockIdx.y;                     // 0..63
    int bj0 = bi + blockIdx.x * 3;
    if (bj0 > 63) return;                     // inactive block, uniform exit
    int ntiles = min(3, 64 - bj0);
    int S = 2 * ntiles;                       // 64-row stages
    int iBase = bi * 128;

    int t    = threadIdx.x;
    int lane = t & 63;
    int wave = t >> 6;
    int col  = lane & 15;
    int quad = lane >> 4;
    int wm = wave >> 1, wn = wave & 1;

    // staging addresses (granule id = q*256 + t; row = q*16 + rowL;
    // slot pos (t&15) holds k-chunk (t&15)^rowL — verified XOR swizzle)
    int rowL  = t >> 4;
    int chunk = (t & 15) ^ rowL;

    // ---- prologue: stage A (128 rows) + B stage 0 (64 rows) concurrently ----
    {
        const unsigned char* gA = zn8 + (size_t)(iBase + rowL) * DDIM + chunk * 16;
        #pragma unroll
        for (int q = 0; q < 8; q++)
            load_lds16(gA + q * 4096, sA + t * 16 + q * 4096);
        const unsigned char* gB = zn8 + (size_t)(bj0 * 128 + rowL) * DDIM + chunk * 16;
        #pragma unroll
        for (int q = 0; q < 4; q++)
            load_lds16(gB + q * 4096, buf0 + t * 16 + q * 4096);
    }
    __syncthreads();

    // ---- A-fragments -> registers (once per chunk, via ds_read) ----
    i32x8 af[4][2];
    {
        const unsigned char* aRow = sA + (size_t)(wm * 64 + col) * DDIM;
        #pragma unroll
        for (int mt = 0; mt < 4; mt++)
            #pragma unroll
            for (int ks = 0; ks < 2; ks++) {
                int g0 = ks * 8 + quad * 2;
                i32x4 lo = *(const i32x4*)(aRow + mt * 16 * DDIM + ((g0    ) ^ col) * 16);
                i32x4 hi = *(const i32x4*)(aRow + mt * 16 * DDIM + ((g0 + 1) ^ col) * 16);
                af[mt][ks] = __builtin_shufflevector(lo, hi, 0, 1, 2, 3, 4, 5, 6, 7);
            }
    }
    __syncthreads();   // all waves done with sA (lgkm-only drain); sA dead

    float rs[4][4];                     // row-sums, accumulated across the chunk
    #pragma unroll
    for (int mt = 0; mt < 4; mt++)
        #pragma unroll
        for (int r = 0; r < 4; r++) rs[mt][r] = 0.f;

    for (int s = 0; s < S; s++) {
        if (s) __syncthreads();          // drains stage s (issued one phase ago)

        // prefetch stage s+1 into the other buffer (flies during compute)
        if (s + 1 < S) {
            int bjn = bj0 + ((s + 1) >> 1), hn = (s + 1) & 1;
            const unsigned char* g =
                zn8 + (size_t)(bjn * 128 + hn * 64 + rowL) * DDIM + chunk * 16;
            unsigned char* dst = ((s + 1) & 1) ? buf1 : buf0;
            #pragma unroll
            for (int q = 0; q < 4; q++)
                load_lds16(g + q * 4096, dst + t * 16 + q * 4096);
        }

        // ---- compute stage s (R12 per-half body) ----
        int bj = bj0 + (s >> 1), h = s & 1;
        int jBase = bj * 128;
        bool isDiag = (bj == bi);
        const unsigned char* bRow =
            (((s & 1) ? buf1 : buf0)) + (size_t)(wn * 32 + col) * DDIM;

        i32x8 bfr[2][2];
        #pragma unroll
        for (int nt = 0; nt < 2; nt++)
            #pragma unroll
            for (int ks = 0; ks < 2; ks++) {
                int g0 = ks * 8 + quad * 2;
                i32x4 lo = *(const i32x4*)(bRow + nt * 16 * DDIM + ((g0    ) ^ col) * 16);
                i32x4 hi = *(const i32x4*)(bRow + nt * 16 * DDIM + ((g0 + 1) ^ col) * 16);
                bfr[nt][ks] = __builtin_shufflevector(lo, hi, 0, 1, 2, 3, 4, 5, 6, 7);
            }

        float cs[2] = {0.f, 0.f};
        #pragma unroll
        for (int mt = 0; mt < 4; mt++) {
            int gi = iBase + wm * 64 + mt * 16;
            #pragma unroll
            for (int nt = 0; nt < 2; nt++) {
                f32x4 acc = {0.f, 0.f, 0.f, 0.f};
                acc = __builtin_amdgcn_mfma_scale_f32_16x16x128_f8f6f4(
                          af[mt][0], bfr[nt][0], acc, 0, 0, 0, SCALE1, 0, SCALE1);
                acc = __builtin_amdgcn_mfma_scale_f32_16x16x128_f8f6f4(
                          af[mt][1], bfr[nt][1], acc, 0, 0, 0, SCALE1, 0, SCALE1);
                bool dtile = (gi == jBase + h * 64 + wn * 32 + nt * 16);
                float csl = 0.f;
                #pragma unroll
                for (int r = 0; r < 4; r++) {
                    float e = exp2f(acc[r] * TWO_LOG2E);
                    if (dtile && (quad * 4 + r) == col) e = 0.f;
                    rs[mt][r] += e;
                    csl += e;
                }
                cs[nt] += csl;
            }
        }

        // col-sums for this stage (off-diag tiles only)
        if (!isDiag) {
            #pragma unroll
            for (int nt = 0; nt < 2; nt++) {
                float v = cs[nt];
                v += __shfl_xor(v, 16);
                v += __shfl_xor(v, 32);
                if (quad == 0)
                    atomicAdd(&denom[jBase + h * 64 + wn * 32 + nt * 16 + col], v);
            }
        }
    }

    // ---- epilogue (once per chunk): row-sum reduce + combine + 128 atomics ----
    #pragma unroll
    for (int mt = 0; mt < 4; mt++)
        #pragma unroll
        for (int r = 0; r < 4; r++) {
            float v = rs[mt][r];
            v += __shfl_xor(v, 1);
            v += __shfl_xor(v, 2);
            v += __shfl_xor(v, 4);
            v += __shfl_xor(v, 8);
            rs[mt][r] = v;
        }
    float* red = (float*)sMem;           // [0:2K) — dead since af barrier
    if (col == 0) {
        #pragma unroll
        for (int mt = 0; mt < 4; mt++)
            #pragma unroll
            for (int r = 0; r < 4; r++)
                red[wn * 128 + wm * 64 + mt * 16 + quad * 4 + r] = rs[mt][r];
    }
    __syncthreads();
    if (t < 128)
        atomicAdd(&denom[iBase + t], red[t] + red[128 + t]);
}

// Kernel 3: final reduction, 32 blocks, atomic into prep-zeroed out[0].
__global__ __launch_bounds__(256) void loss_kernel(const float* __restrict__ posPart,
                                                   const float* __restrict__ denom,
                                                   float* __restrict__ out) {
    __shared__ float sdata[4];
    int t = threadIdx.x;
    float s = __logf(denom[blockIdx.x * 256 + t]);
    if (t < 32) s -= 2.0f * posPart[blockIdx.x * 32 + t];
    #pragma unroll
    for (int off = 32; off; off >>= 1) s += __shfl_xor(s, off);
    if ((t & 63) == 0) sdata[t >> 6] = s;
    __syncthreads();
    if (t == 0)
        atomicAdd(out, (sdata[0] + sdata[1] + sdata[2] + sdata[3]) * (1.0f / NROWS));
}

extern "C" void kernel_launch(void* const* d_in, const int* in_sizes, int n_in,
                              void* d_out, int out_size, void* d_ws, size_t ws_size,
                              hipStream_t stream) {
    const float* z1 = (const float*)d_in[0];
    const float* z2 = (const float*)d_in[1];

    // ws: zn8 fp8 [8192*256] (2 MB) | denom f32[8192] | posPart f32[1024]
    unsigned char* zn8 = (unsigned char*)d_ws;
    float* denom   = (float*)((char*)d_ws + (size_t)NROWS * DDIM);
    float* posPart = denom + NROWS;

    prep_kernel<<<BHALF / 4, 256, 0, stream>>>(z1, z2, zn8, posPart, denom, (float*)d_out);
    denom_kernel<<<dim3(22, 64), 256, 0, stream>>>(zn8, denom);
    loss_kernel<<<NROWS / 256, 256, 0, stream>>>(posPart, denom, (float*)d_out);
}